// Round 8
// baseline (93.788 us; speedup 1.0000x reference)
//
#include <hip/hip_runtime.h>
#include <math.h>

#define NF 16384        // fast-path n
#define NB 2048         // value buckets (monotone map => exact; ~8 members avg)
#define TPB 256         // threads per block
#define NBLK (NF/TPB)   // 64 blocks, one element per thread
#define PBK (NB/TPB)    // 8 buckets per thread in scans/reductions
#define BLOCK 256       // fallback block size

__device__ __forceinline__ int bucket_of(float t) {
    int b = (int)((t + 6.0f) * (NB / 12.0f));   // monotone (non-decreasing) in t
    return min(max(b, 0), NB - 1);
}

// K1: per-block LDS histogram -> per-block SLAB (plain stores, no zero-init,
// no global atomics, no memset anywhere). Also: Earr, per-element in-block
// rank (free from the LDS cursor), ticket=0.
__global__ __launch_bounds__(TPB) void surv_hist(
        const float* __restrict__ theta, const float* __restrict__ T,
        float* __restrict__ Earr, int* __restrict__ rank,
        int* __restrict__ slabC, float* __restrict__ slabE,
        int* __restrict__ ticket) {
    __shared__ int   lc[NB];
    __shared__ float le[NB];
    const int tid = threadIdx.x;
    const int g   = blockIdx.x;

    #pragma unroll
    for (int k = 0; k < PBK; ++k) { lc[tid + k * TPB] = 0; le[tid + k * TPB] = 0.f; }
    __syncthreads();

    const int i = g * TPB + tid;
    const float Tv = T[i];
    const float Ev = expf(theta[i]);
    const int b = bucket_of(Tv);
    Earr[i] = Ev;
    rank[i] = atomicAdd(&lc[b], 1);      // in-block, in-bucket rank (LDS atomic)
    atomicAdd(&le[b], Ev);
    __syncthreads();

    #pragma unroll
    for (int k = 0; k < PBK; ++k) {      // coalesced slab write (8 KB/block)
        slabC[g * NB + tid + k * TPB] = lc[tid + k * TPB];
        slabE[g * NB + tid + k * TPB] = le[tid + k * TPB];
    }
    if (g == 0 && tid == 0) *ticket = 0;
}

// K2: redundant slab-reduce per block (1 MB L2-resident; 64 MB total ~2us).
// While reducing, snapshot this block's cross-block offset off_g[b] =
// sum_{s<g} slab_s[b] -> scatter position is DETERMINISTIC (no cursors).
// Dual Hillis-Steele scan (proven); block 0 publishes pfx/sfx; all blocks
// scatter their 256 elements with plain stores.
__global__ __launch_bounds__(TPB) void surv_scan_scatter(
        const float* __restrict__ T, const float* __restrict__ Earr,
        const int* __restrict__ rank,
        const int* __restrict__ slabC, const float* __restrict__ slabE,
        int* __restrict__ pfxg, float* __restrict__ sfxg,
        float2* __restrict__ sorted) {
    __shared__ int   pfx[NB];      // exclusive prefix of counts
    __shared__ int   offg[NB];     // this block's cross-block offset
    __shared__ float sfx[NB];      // exclusive suffix of bucket E-sums
    __shared__ int   sc[TPB];
    __shared__ float se[TPB];

    const int tid  = threadIdx.x;
    const int g    = blockIdx.x;
    const int base = tid * PBK;

    int ct[PBK]; float et[PBK]; int og[PBK];
    #pragma unroll
    for (int k = 0; k < PBK; ++k) { ct[k] = 0; et[k] = 0.f; og[k] = 0; }
    for (int s = 0; s < NBLK; ++s) {               // coalesced: 8 consec/thread
        #pragma unroll
        for (int k = 0; k < PBK; ++k) {
            const int   c = slabC[s * NB + base + k];
            const float e = slabE[s * NB + base + k];
            if (s == g) og[k] = ct[k];             // prefix BEFORE my slab
            ct[k] += c; et[k] += e;
        }
    }
    int cs = 0; float es = 0.f;
    #pragma unroll
    for (int k = 0; k < PBK; ++k) { cs += ct[k]; es += et[k]; }
    sc[tid] = cs; se[tid] = es;
    __syncthreads();
    for (int s = 1; s < TPB; s <<= 1) {            // proven dual Hillis-Steele
        const int   a = (tid >= s)      ? sc[tid - s] : 0;
        const float f = (tid + s < TPB) ? se[tid + s] : 0.f;
        __syncthreads();
        sc[tid] += a; se[tid] += f;
        __syncthreads();
    }
    {   int run = sc[tid] - cs;                    // exclusive prefix
        #pragma unroll
        for (int k = 0; k < PBK; ++k) {
            pfx[base + k] = run; offg[base + k] = og[k]; run += ct[k];
        }
    }
    {   float rs = se[tid] - es;                   // exclusive suffix
        #pragma unroll
        for (int k = PBK - 1; k >= 0; --k) { sfx[base + k] = rs; rs += et[k]; }
    }
    __syncthreads();

    if (g == 0) {                                  // publish for K3
        for (int idx = tid; idx < NB; idx += TPB) {
            pfxg[idx] = pfx[idx]; sfxg[idx] = sfx[idx];
        }
        if (tid == 0) pfxg[NB] = NF;
    }

    // deterministic scatter of this block's 256 elements (plain stores)
    const int i = g * TPB + tid;
    const float Tv = T[i];
    const int b = bucket_of(Tv);
    sorted[pfx[b] + offg[b] + rank[i]] = make_float2(Tv, Earr[i]);
}

// K3: exact risk = suffix of buckets above + ~8-member in-bucket compare
// loop; term; block reduce; proven ticket epilogue (64 parallel coherent
// RMW reads in the last block).
__global__ __launch_bounds__(TPB) void surv_risk(
        const float* __restrict__ theta, const float* __restrict__ T,
        const float* __restrict__ events,
        const int* __restrict__ pfxg, const float* __restrict__ sfxg,
        const float2* __restrict__ sorted,
        float* __restrict__ bsum, int* __restrict__ ticket,
        float* __restrict__ out) {
    __shared__ float ws4[TPB / 64];
    __shared__ int last;

    const int tid = threadIdx.x;
    const int i = blockIdx.x * TPB + tid;
    const float Tv = T[i];
    const int b = bucket_of(Tv);
    float r = sfxg[b];
    const int p1 = pfxg[b + 1];
    for (int p = pfxg[b]; p < p1; ++p) {
        const float2 v = sorted[p];
        r += (v.x >= Tv) ? v.y : 0.f;
    }
    float term = (theta[i] - logf(r)) * events[i];

    #pragma unroll
    for (int off = 32; off > 0; off >>= 1) term += __shfl_down(term, off, 64);
    if ((tid & 63) == 0) ws4[tid >> 6] = term;
    __syncthreads();
    if (tid == 0) {
        bsum[blockIdx.x] = ws4[0] + ws4[1] + ws4[2] + ws4[3];  // plain store
        __threadfence();                                       // release
        last = (atomicAdd(ticket, 1) == NBLK - 1) ? 1 : 0;
    }
    __syncthreads();
    if (last && tid < 64) {                      // 64 parallel RMW reads at
        float v = atomicAdd(&bsum[tid], 0.f);    // the coherent point
        #pragma unroll
        for (int off = 32; off > 0; off >>= 1) v += __shfl_down(v, off, 64);
        if (tid == 0) out[0] = -v / (float)NF;
    }
}

// ---------- brute-force fallback (generic n) ----------
__global__ void surv_partial_bf(const float* __restrict__ theta, const float* __restrict__ T,
                                const float* __restrict__ events, float* __restrict__ bsum, int n) {
    __shared__ float red[BLOCK];
    const int tid = threadIdx.x;
    const int i = blockIdx.x * BLOCK + tid;
    float term = 0.f;
    if (i < n) {
        const float Ti = T[i];
        float risk = 0.f;
        for (int j = 0; j < n; ++j)
            risk += (T[j] >= Ti) ? expf(theta[j]) : 0.f;
        term = (theta[i] - logf(risk)) * events[i];
    }
    red[tid] = term;
    __syncthreads();
    for (int s = BLOCK / 2; s > 0; s >>= 1) {
        if (tid < s) red[tid] += red[tid + s];
        __syncthreads();
    }
    if (tid == 0) bsum[blockIdx.x] = red[0];
}

__global__ void surv_final(const float* __restrict__ bsum, float* __restrict__ out,
                           int nblocks, int n) {
    float v = 0.f;
    for (int b = threadIdx.x; b < nblocks; b += 64) v += bsum[b];
    for (int off = 32; off > 0; off >>= 1) v += __shfl_down(v, off, 64);
    if (threadIdx.x == 0) out[0] = -v / (float)n;
}

extern "C" void kernel_launch(void* const* d_in, const int* in_sizes, int n_in,
                              void* d_out, int out_size, void* d_ws, size_t ws_size,
                              hipStream_t stream) {
    const float* theta  = (const float*)d_in[0];
    const float* T      = (const float*)d_in[1];
    const float* events = (const float*)d_in[2];
    float* out = (float*)d_out;
    const int n = in_sizes[0];                  // 16384

    // ws layout (words): slabC[NBLK*NB] | slabE[NBLK*NB] | Earr[NF] | rank[NF]
    //   | pfxg[NB+1] | sfxg[NB] | sorted float2[NF] (2NF) | bsum[NBLK] | ticket
    const size_t need = ((size_t)2 * NBLK * NB + 2 * NF + (NB + 1) + NB
                         + 2 * NF + NBLK + 1) * 4;
    const bool fast = (n == NF) && ((size_t)ws_size >= need);

    if (!fast) {
        const int nbi = (n + BLOCK - 1) / BLOCK;
        float* bsum = (float*)d_ws;
        surv_partial_bf<<<nbi, BLOCK, 0, stream>>>(theta, T, events, bsum, n);
        surv_final<<<1, 64, 0, stream>>>(bsum, out, nbi, n);
        return;
    }

    int*    slabC  = (int*)d_ws;
    float*  slabE  = (float*)(slabC + (size_t)NBLK * NB);
    float*  Earr   = slabE + (size_t)NBLK * NB;
    int*    rank   = (int*)(Earr + NF);
    int*    pfxg   = rank + NF;
    float*  sfxg   = (float*)(pfxg + NB + 1);
    float2* sorted = (float2*)(sfxg + NB);
    float*  bsum   = (float*)(sorted + NF);
    int*    ticket = (int*)(bsum + NBLK);

    surv_hist<<<NBLK, TPB, 0, stream>>>(theta, T, Earr, rank, slabC, slabE, ticket);
    surv_scan_scatter<<<NBLK, TPB, 0, stream>>>(T, Earr, rank, slabC, slabE,
                                                pfxg, sfxg, sorted);
    surv_risk<<<NBLK, TPB, 0, stream>>>(theta, T, events, pfxg, sfxg, sorted,
                                        bsum, ticket, out);
}

// Round 9
// 93.742 us; speedup vs baseline: 1.0005x; 1.0005x over previous
//
#include <hip/hip_runtime.h>
#include <math.h>

#define NF 16384        // fast-path n
#define NB 2048         // value buckets (monotone map => exact; proven R0-R8)
#define HT 256          // hist threads
#define HBLK (NF/HT)    // 64 hist blocks, 1 element/thread
#define ST 1024         // solve threads (16 waves)
#define SBLK 64         // solve blocks; each owns NB/SBLK buckets
#define BPB (NB/SBLK)   // 32 buckets per solve block
#define EPT (NF/ST)     // 16 elements scanned per solve thread
#define CAP 4096        // LDS pool capacity (center block ~1230 expected)
#define BLOCK 256       // fallback block size

__device__ __forceinline__ int bucket_of(float t) {
    int b = (int)((t + 6.0f) * (NB / 12.0f));   // monotone (non-decreasing) in t
    return min(max(b, 0), NB - 1);
}

// K1: per-block LDS E-histogram (256 LDS atomics/block only) -> linear slab
// (coalesced plain stores; no memset, no global atomics). ticket=0.
__global__ __launch_bounds__(HT) void surv_hist(
        const float* __restrict__ theta, const float* __restrict__ T,
        float* __restrict__ slab, int* __restrict__ ticket) {
    __shared__ float h[NB];
    const int tid = threadIdx.x, g = blockIdx.x;
    #pragma unroll
    for (int k = 0; k < NB / HT; ++k) h[tid + k * HT] = 0.f;
    __syncthreads();
    const int i = g * HT + tid;
    atomicAdd(&h[bucket_of(T[i])], expf(theta[i]));
    __syncthreads();
    #pragma unroll
    for (int k = 0; k < NB / HT; ++k)
        slab[g * NB + tid + k * HT] = h[tid + k * HT];   // coalesced 8 KB
    if (g == 0 && tid == 0) *ticket = 0;
}

// K2: everything else, one dispatch. Per block: (1) column-reduce slab
// (coalesced float2; 512 KB L3-resident), (2) suffix-scan 2048 buckets
// (proven Hillis-Steele), (3) gather members of my 32 owned buckets into a
// bucket-grouped LDS pool, (4) exact per-member term via sfx_excl + short
// in-bucket compare loop, (5) proven ticket epilogue.
__global__ __launch_bounds__(ST) void surv_solve(
        const float* __restrict__ theta, const float* __restrict__ T,
        const float* __restrict__ events, const float* __restrict__ slab,
        float* __restrict__ bsum, int* __restrict__ ticket,
        float* __restrict__ out) {
    __shared__ float sfx[NB];          // exclusive suffix of bucket totals
    __shared__ float se[ST];
    __shared__ int   cntl[BPB], sbase[BPB + 1];
    __shared__ float pT[CAP], pE[CAP];
    __shared__ int   pJ[CAP], pB[CAP];
    __shared__ float red[ST / 64];
    __shared__ int   Mtot, last;

    const int tid = threadIdx.x, g = blockIdx.x;
    const int blo = g * BPB;

    // (1) bucket totals for my 2 buckets (wave reads 512 B contiguous)
    const int b0 = 2 * tid;
    float e0 = 0.f, e1 = 0.f;
    for (int s = 0; s < HBLK; ++s) {
        const float2 v = *(const float2*)&slab[s * NB + b0];
        e0 += v.x; e1 += v.y;
    }
    const float es = e0 + e1;
    se[tid] = es;
    __syncthreads();
    // (2) suffix Hillis-Steele over thread chunk-sums (proven pattern)
    for (int s = 1; s < ST; s <<= 1) {
        const float f = (tid + s < ST) ? se[tid + s] : 0.f;
        __syncthreads();
        se[tid] += f;
        __syncthreads();
    }
    {   const float rs = se[tid] - es;   // exclusive suffix of chunk sums
        sfx[b0 + 1] = rs;                // sum of buckets > b0+1
        sfx[b0]     = rs + e1;           // sum of buckets > b0
    }
    if (tid < BPB) cntl[tid] = 0;
    __syncthreads();

    // (3a) count members of my bucket range
    #pragma unroll
    for (int k = 0; k < EPT; ++k) {
        const int j = tid + k * ST;                      // coalesced
        const int b = bucket_of(T[j]) - blo;
        if ((unsigned)b < BPB) atomicAdd(&cntl[b], 1);
    }
    __syncthreads();
    if (tid == 0) {
        int run = 0;
        for (int b = 0; b < BPB; ++b) { sbase[b] = run; run += cntl[b]; cntl[b] = 0; }
        sbase[BPB] = run; Mtot = run;
    }
    __syncthreads();
    const int M = Mtot;

    float acc = 0.f;
    if (M <= CAP) {
        // (3b) place, grouped by bucket
        #pragma unroll
        for (int k = 0; k < EPT; ++k) {
            const int j = tid + k * ST;
            const float Tv = T[j];
            const int b = bucket_of(Tv) - blo;
            if ((unsigned)b < BPB) {
                const int pos = sbase[b] + atomicAdd(&cntl[b], 1);
                pT[pos] = Tv; pE[pos] = expf(theta[j]); pJ[pos] = j; pB[pos] = b;
            }
        }
        __syncthreads();
        // (4) exact term per member: ~40-member in-bucket compare loop
        for (int e = tid; e < M; e += ST) {
            const int b = pB[e];
            const float Ti = pT[e];
            float risk = sfx[blo + b];
            const int p1 = sbase[b + 1];
            for (int p = sbase[b]; p < p1; ++p)
                risk += (pT[p] >= Ti) ? pE[p] : 0.f;
            const int j = pJ[e];
            acc += (theta[j] - logf(risk)) * events[j];
        }
    } else {
        // overflow (never on benchmark data): exact brute path, same answer
        for (int j = tid; j < NF; j += ST) {
            const float Ti = T[j];
            const int b = bucket_of(Ti);
            if (b < blo || b >= blo + BPB) continue;
            float risk = sfx[b];
            for (int j2 = 0; j2 < NF; ++j2)
                if (bucket_of(T[j2]) == b && T[j2] >= Ti) risk += expf(theta[j2]);
            acc += (theta[j] - logf(risk)) * events[j];
        }
    }

    // (5) block reduce + proven ticket epilogue
    #pragma unroll
    for (int off = 32; off > 0; off >>= 1) acc += __shfl_down(acc, off, 64);
    if ((tid & 63) == 0) red[tid >> 6] = acc;
    __syncthreads();
    if (tid == 0) {
        float bs = 0.f;
        #pragma unroll
        for (int w = 0; w < ST / 64; ++w) bs += red[w];
        bsum[g] = bs;                    // plain store
        __threadfence();                 // release before ticket
        last = (atomicAdd(ticket, 1) == SBLK - 1) ? 1 : 0;
    }
    __syncthreads();
    if (last && tid < 64) {              // 64 parallel coherent-point RMW reads
        float v = atomicAdd(&bsum[tid & 63], 0.f);
        v = (tid < SBLK) ? v : 0.f;
        #pragma unroll
        for (int off = 32; off > 0; off >>= 1) v += __shfl_down(v, off, 64);
        if (tid == 0) out[0] = -v / (float)NF;
    }
}

// ---------- brute-force fallback (generic n) ----------
__global__ void surv_partial_bf(const float* __restrict__ theta, const float* __restrict__ T,
                                const float* __restrict__ events, float* __restrict__ bsum, int n) {
    __shared__ float red[BLOCK];
    const int tid = threadIdx.x;
    const int i = blockIdx.x * BLOCK + tid;
    float term = 0.f;
    if (i < n) {
        const float Ti = T[i];
        float risk = 0.f;
        for (int j = 0; j < n; ++j)
            risk += (T[j] >= Ti) ? expf(theta[j]) : 0.f;
        term = (theta[i] - logf(risk)) * events[i];
    }
    red[tid] = term;
    __syncthreads();
    for (int s = BLOCK / 2; s > 0; s >>= 1) {
        if (tid < s) red[tid] += red[tid + s];
        __syncthreads();
    }
    if (tid == 0) bsum[blockIdx.x] = red[0];
}

__global__ void surv_final(const float* __restrict__ bsum, float* __restrict__ out,
                           int nblocks, int n) {
    float v = 0.f;
    for (int b = threadIdx.x; b < nblocks; b += 64) v += bsum[b];
    for (int off = 32; off > 0; off >>= 1) v += __shfl_down(v, off, 64);
    if (threadIdx.x == 0) out[0] = -v / (float)n;
}

extern "C" void kernel_launch(void* const* d_in, const int* in_sizes, int n_in,
                              void* d_out, int out_size, void* d_ws, size_t ws_size,
                              hipStream_t stream) {
    const float* theta  = (const float*)d_in[0];
    const float* T      = (const float*)d_in[1];
    const float* events = (const float*)d_in[2];
    float* out = (float*)d_out;
    const int n = in_sizes[0];                  // 16384

    // ws layout (words): slab[HBLK*NB] | bsum[SBLK] | ticket
    const size_t need = ((size_t)HBLK * NB + SBLK + 1) * 4;
    const bool fast = (n == NF) && ((size_t)ws_size >= need);

    if (!fast) {
        const int nbi = (n + BLOCK - 1) / BLOCK;
        float* bsum = (float*)d_ws;
        surv_partial_bf<<<nbi, BLOCK, 0, stream>>>(theta, T, events, bsum, n);
        surv_final<<<1, 64, 0, stream>>>(bsum, out, nbi, n);
        return;
    }

    float* slab   = (float*)d_ws;
    float* bsum   = slab + (size_t)HBLK * NB;
    int*   ticket = (int*)(bsum + SBLK);

    surv_hist<<<HBLK, HT, 0, stream>>>(theta, T, slab, ticket);
    surv_solve<<<SBLK, ST, 0, stream>>>(theta, T, events, slab, bsum, ticket, out);
}

// Round 10
// 78.721 us; speedup vs baseline: 1.1914x; 1.1908x over previous
//
#include <hip/hip_runtime.h>
#include <math.h>

#define MT 1024          // main kernel threads: 16 waves
#define NW 16            // waves per block
#define IPG 512          // i's per group (8 per lane): 48 VALU per ds_read_b128
#define NSPLIT 16        // j-splits per group (grid = (n/IPG)*NSPLIT)
#define MAXJ 2048        // max j's staged in LDS per block
#define FBLOCK 256       // finalize block size
#define BLOCK 256        // fallback block size

// K1: O(n^2) sweep. Block (g,s): i-group g (512 i's, 8/lane), j-split s.
//  Best-measured structure of the session (R4: 79.3 us total). All O(n)
//  bucket variants (R5-R9) measured slower (83.3-98.4) despite less work:
//  their cross-block coherence/latency costs exceed the n^2 VALU savings.
__global__ __launch_bounds__(MT, 8) void surv_main(
        const float* __restrict__ theta, const float* __restrict__ T,
        float* __restrict__ partial, float* __restrict__ accum,
        int* __restrict__ ticket, int n) {
    __shared__ float2 sPE[MAXJ];      // staged (T, E) pairs (8 KB used @ n=16K)
    __shared__ float part[NW][IPG];   // 32 KB cross-wave partials

    const int tid  = threadIdx.x;
    const int w    = tid >> 6;
    const int lane = tid & 63;
    const int g    = blockIdx.x >> 4;          // i-group
    const int s    = blockIdx.x & (NSPLIT-1);  // j-split
    const int ibase = g * IPG;

    if (blockIdx.x == 0 && tid == 0) { *accum = 0.f; *ticket = 0; }

    // stage this block's j-slice (1024 elems @ n=16K: one per thread)
    const int jcount = n / NSPLIT;
    const int j0 = s * jcount;
    for (int j = tid; j < jcount; j += MT)
        sPE[j] = make_float2(T[j0 + j], expf(theta[j0 + j]));

    // 8 i's per lane, coalesced
    float Ti[8];
    #pragma unroll
    for (int k = 0; k < 8; ++k) Ti[k] = T[ibase + k * 64 + lane];
    __syncthreads();

    const int jw = jcount / NW;                // j's per wave (64 @ n=16K)
    const int nq = jw >> 1;                    // float4 (2-pair) reads (32)
    const float4* sPE4 = (const float4*)sPE;
    const int qb = (w * jw) >> 1;              // wave-uniform LDS base

    float accA[8], accB[8];
    #pragma unroll
    for (int k = 0; k < 8; ++k) { accA[k] = 0.f; accB[k] = 0.f; }

    #pragma unroll 8
    for (int q = 0; q < nq; ++q) {
        float4 v = sPE4[qb + q];               // broadcast ds_read_b128
        #pragma unroll
        for (int k = 0; k < 8; ++k) {
            accA[k] += (v.x >= Ti[k]) ? v.y : 0.f;
            accB[k] += (v.z >= Ti[k]) ? v.w : 0.f;
        }
    }
    #pragma unroll
    for (int k = 0; k < 8; ++k)
        part[w][k * 64 + lane] = accA[k] + accB[k];
    __syncthreads();

    // cross-wave reduce; plain stores (dispatch boundary publishes to K2)
    for (int idx = tid; idx < IPG; idx += MT) {
        float v = 0.f;
        #pragma unroll
        for (int ww = 0; ww < NW; ++ww) v += part[ww][idx];
        partial[(size_t)s * n + ibase + idx] = v;
    }
}

// K2: finalize. Sum the 16 split-partials per i, log-term, reduce,
// tiny atomic+ticket in-kernel output (64 blocks - proven cheap).
__global__ __launch_bounds__(FBLOCK) void surv_fin(
        const float* __restrict__ theta, const float* __restrict__ events,
        const float* __restrict__ partial, float* __restrict__ accum,
        int* __restrict__ ticket, float* __restrict__ out, int n) {
    __shared__ float red[FBLOCK];
    const int tid = threadIdx.x;
    const int i = blockIdx.x * FBLOCK + tid;
    float r = 0.f;
    #pragma unroll
    for (int s = 0; s < NSPLIT; ++s) r += partial[(size_t)s * n + i];
    red[tid] = (theta[i] - logf(r)) * events[i];
    __syncthreads();
    for (int s = FBLOCK / 2; s > 0; s >>= 1) {
        if (tid < s) red[tid] += red[tid + s];
        __syncthreads();
    }
    if (tid == 0) {
        atomicAdd(accum, red[0]);
        __threadfence();
        int t = atomicAdd(ticket, 1);
        if (t == (int)gridDim.x - 1) {
            float tot = atomicAdd(accum, 0.f);   // RMW read at coherent point
            out[0] = -tot / (float)n;
        }
    }
}

// ---------- brute-force fallback (generic n) ----------
__global__ void surv_partial_bf(const float* __restrict__ theta, const float* __restrict__ T,
                                const float* __restrict__ events, float* __restrict__ bsum, int n) {
    __shared__ float red[BLOCK];
    const int tid = threadIdx.x;
    const int i = blockIdx.x * BLOCK + tid;
    float term = 0.f;
    if (i < n) {
        const float Ti = T[i];
        float risk = 0.f;
        for (int j = 0; j < n; ++j)
            risk += (T[j] >= Ti) ? expf(theta[j]) : 0.f;
        term = (theta[i] - logf(risk)) * events[i];
    }
    red[tid] = term;
    __syncthreads();
    for (int s = BLOCK / 2; s > 0; s >>= 1) {
        if (tid < s) red[tid] += red[tid + s];
        __syncthreads();
    }
    if (tid == 0) bsum[blockIdx.x] = red[0];
}

__global__ void surv_final(const float* __restrict__ bsum, float* __restrict__ out,
                           int nblocks, int n) {
    float v = 0.f;
    for (int b = threadIdx.x; b < nblocks; b += 64) v += bsum[b];
    for (int off = 32; off > 0; off >>= 1) v += __shfl_down(v, off, 64);
    if (threadIdx.x == 0) out[0] = -v / (float)n;
}

extern "C" void kernel_launch(void* const* d_in, const int* in_sizes, int n_in,
                              void* d_out, int out_size, void* d_ws, size_t ws_size,
                              hipStream_t stream) {
    const float* theta  = (const float*)d_in[0];
    const float* T      = (const float*)d_in[1];
    const float* events = (const float*)d_in[2];
    float* out = (float*)d_out;
    const int n = in_sizes[0];                  // 16384

    // fast path: n % 2048 == 0 (512-i groups, 16 splits, 16 waves, float4-even),
    // j-slice fits LDS stage, FBLOCK divides n.
    // ws: partial[NSPLIT][n] f32 | accum | ticket
    const size_t need = (size_t)NSPLIT * n * 4 + 64;
    const bool fast = (n >= 2048) && (n % 2048 == 0) && (n / NSPLIT <= MAXJ)
                      && ((size_t)ws_size >= need);

    if (!fast) {
        const int nbi = (n + BLOCK - 1) / BLOCK;
        float* bsum = (float*)d_ws;
        surv_partial_bf<<<nbi, BLOCK, 0, stream>>>(theta, T, events, bsum, n);
        surv_final<<<1, 64, 0, stream>>>(bsum, out, nbi, n);
        return;
    }

    float* partial = (float*)d_ws;
    float* accum   = partial + (size_t)NSPLIT * n;
    int*   ticket  = (int*)(accum + 1);

    const int ng = n / IPG;                     // 32
    const int mb = ng * NSPLIT;                 // 512 blocks
    const int fb = n / FBLOCK;                  // 64 blocks

    surv_main<<<mb, MT, 0, stream>>>(theta, T, partial, accum, ticket, n);
    surv_fin<<<fb, FBLOCK, 0, stream>>>(theta, events, partial, accum, ticket, out, n);
}